// Round 4
// baseline (266.432 us; speedup 1.0000x reference)
//
#include <hip/hip_runtime.h>

#define MDIM 32768
#define NDIM 4096
#define KDIM 1024

typedef __attribute__((ext_vector_type(4))) float floatx4;
typedef __attribute__((ext_vector_type(16))) float float16v;
typedef __attribute__((ext_vector_type(4))) int int4v;
typedef __attribute__((ext_vector_type(8))) int int8v;

// ---- quantize x: f32 [M,K] -> fp8 e4m3 bytes [M,K] (RNE, saturating) ----
__global__ __launch_bounds__(256) void quant_x_kernel(
    const float* __restrict__ x, char* __restrict__ out, int n16) {
    int idx = blockIdx.x * blockDim.x + threadIdx.x;
    int stride = gridDim.x * blockDim.x;
    const floatx4* xv = (const floatx4*)x;
    int4v* ov = (int4v*)out;
    for (int i = idx; i < n16; i += stride) {
        int4v o;
#pragma unroll
        for (int j = 0; j < 4; ++j) {
            floatx4 v = xv[i * 4 + j];
            int pk = __builtin_amdgcn_cvt_pk_fp8_f32(v.x, v.y, 0, false);
            pk = __builtin_amdgcn_cvt_pk_fp8_f32(v.z, v.w, pk, true);
            o[j] = pk;
        }
        ov[i] = o;
    }
}

// ---- quantize + transpose w: f32 [K,N] -> fp8 e4m3 [N,K] ----
__global__ __launch_bounds__(256) void quant_w_kernel(
    const float* __restrict__ w, char* __restrict__ wT) {
    __shared__ char tile[64][68];
    int nbase = blockIdx.x * 64;
    int kbase = blockIdx.y * 64;
    int t = threadIdx.x;
#pragma unroll
    for (int i = 0; i < 4; ++i) {
        int fidx = t + i * 256;      // 1024 float4s per 64x64 tile
        int r = fidx >> 4;           // k row 0..63
        int c4 = fidx & 15;          // float4 col
        floatx4 v = *(const floatx4*)&w[(long)(kbase + r) * NDIM + nbase + c4 * 4];
        int pk = __builtin_amdgcn_cvt_pk_fp8_f32(v.x, v.y, 0, false);
        pk = __builtin_amdgcn_cvt_pk_fp8_f32(v.z, v.w, pk, true);
        *(int*)&tile[r][c4 * 4] = pk;
    }
    __syncthreads();
    int n = t >> 2, kq = (t & 3) * 16;
    int outw[4];
#pragma unroll
    for (int g = 0; g < 4; ++g) {
        int v = 0;
#pragma unroll
        for (int j = 0; j < 4; ++j)
            v |= ((int)(unsigned char)tile[kq + g * 4 + j][n]) << (8 * j);
        outw[g] = v;
    }
    *(int4v*)&wT[(long)(nbase + n) * KDIM + kbase + kq] = *(int4v*)outw;
}

// ======== GEMM: MX-fp8 (unit scales). A fp8 [M,K], BT fp8 [N,K], C f32 [M,N].
// 256x256 tile, BK=64 bytes, 16 K-tiles, 4-deep LDS buffer rotation (3-tile
// lead, vmcnt(12) counted — never drained mid-loop). 8 waves (2M x 4N), wave
// tile 128x64 = 4m x 2n frags of 32x32, mfma_scale 32x32x64 (scale 0x7F = 2^0).
// LDS buf d (32 KB): A at d*32768 (128 rows x 128 B; row r packs M-rows r and
// r+128 as two 64 B halves), B at +16384 (same for N-rows). Rows are 8 chunks
// of 16 B with XOR swizzle chunk ^= row&7 (both-sides involution; zero
// conflicts measured in rounds 1-3). 4 global_load_lds dwordx4 per tile.

#define GL(gp, lp)                                                 \
    __builtin_amdgcn_global_load_lds(                              \
        (const __attribute__((address_space(1))) void*)(gp),       \
        (__attribute__((address_space(3))) void*)(lp), 16, 0, 0)

#define VMCNT(n) asm volatile("s_waitcnt vmcnt(" #n ")" ::: "memory")
#define BARS()  { __builtin_amdgcn_s_barrier(); __builtin_amdgcn_sched_barrier(0); }

#define MFMA_SC(a_, b_, c_)                                               \
    __builtin_amdgcn_mfma_scale_f32_32x32x64_f8f6f4(                      \
        (a_), (b_), (c_), 0, 0, 0, 0x7F7F7F7F, 0, 0x7F7F7F7F)

__global__ __launch_bounds__(512) void gemm_kernel(
    const char* __restrict__ A, const char* __restrict__ BT,
    const float* __restrict__ bias, float* __restrict__ C) {
    __shared__ char lds[131072];   // buf d: A at d*32768, B at d*32768+16384

    const int T = threadIdx.x;
    const int lane = T & 63;
    const int w = T >> 6;            // wave 0..7
    const int wr = w >> 2;           // 0..1 (M)
    const int wc = w & 3;            // 0..3 (N)

    // XCD-aware bijective swizzle (2048 blocks % 8 == 0), bn-major chunks.
    const int sw = (blockIdx.x & 7) * 256 + (blockIdx.x >> 3);
    const int bn = (sw >> 7) * 256;      // 16 N-blocks
    const int bm = (sw & 127) * 256;     // 128 M-blocks

    // ---- staging (per-thread): LDS slab-row (T>>3), phys chunk (T&7).
    // Logical chunk cs = (T&7)^((T>>3)&7); chunk c holds M-row r+128*(c>>2),
    // k-byte (c&3)*16 of the tile's 64 B slice.
    const int cs = (T & 7) ^ ((T >> 3) & 7);
    const int srcRow = (T >> 3) + 128 * (cs >> 2);
    const int kByte = (cs & 3) * 16;
    const long aOff = (long)(bm + srcRow) * KDIM + kByte;
    const long bOff = (long)(bn + srcRow) * KDIM + kByte;
    const int dstB = (T >> 3) * 128 + (T & 7) * 16;   // within 8 KB slab

#define STAGE(d_, t_) {                                                   \
        char* la_ = lds + (d_) * 32768 + dstB;                            \
        char* lb_ = la_ + 16384;                                          \
        const char* ga_ = A + aOff + (t_) * 64;                           \
        const char* gb_ = BT + bOff + (t_) * 64;                          \
        GL(ga_, la_);  GL(ga_ + 64 * KDIM, la_ + 8192);                   \
        GL(gb_, lb_);  GL(gb_ + 64 * KDIM, lb_ + 8192);                   \
    }

    // ---- read-side addresses ----
    const int l31 = lane & 31;
    const int kh = lane >> 5;                 // k half
    const int swz = (l31 & 7) << 4;
    const int col0A = 64 * wr + 32 * kh;      // logical byte col (A half = wr)
    const int col0B = 64 * (wc >> 1) + 32 * kh;
    const char* Abase = lds + l31 * 128;
    const char* Bbase = lds + 16384 + ((wc & 1) * 64 + l31) * 128;

    float16v acc[4][2] = {};

#define LD32(dst_, base_, col0_) {                                        \
        int4v lo_ = *(const int4v*)((base_) + (((col0_) + 0) ^ swz));     \
        int4v hi_ = *(const int4v*)((base_) + (((col0_) + 16) ^ swz));    \
        dst_[0] = lo_[0]; dst_[1] = lo_[1]; dst_[2] = lo_[2]; dst_[3] = lo_[3]; \
        dst_[4] = hi_[0]; dst_[5] = hi_[1]; dst_[6] = hi_[2]; dst_[7] = hi_[3]; \
    }

#define COMPUTE(d_) {                                                     \
        const char* ap_ = Abase + (d_) * 32768;                           \
        const char* bp_ = Bbase + (d_) * 32768;                           \
        int8v a0, a1, a2, a3, b0, b1;                                     \
        LD32(b0, bp_, col0B);        LD32(b1, bp_ + 4096, col0B);         \
        LD32(a0, ap_, col0A);        LD32(a1, ap_ + 4096, col0A);         \
        LD32(a2, ap_ + 8192, col0A); LD32(a3, ap_ + 12288, col0A);        \
        __builtin_amdgcn_s_setprio(1);                                    \
        acc[0][0] = MFMA_SC(a0, b0, acc[0][0]);                           \
        acc[0][1] = MFMA_SC(a0, b1, acc[0][1]);                           \
        acc[1][0] = MFMA_SC(a1, b0, acc[1][0]);                           \
        acc[1][1] = MFMA_SC(a1, b1, acc[1][1]);                           \
        acc[2][0] = MFMA_SC(a2, b0, acc[2][0]);                           \
        acc[2][1] = MFMA_SC(a2, b1, acc[2][1]);                           \
        acc[3][0] = MFMA_SC(a3, b0, acc[3][0]);                           \
        acc[3][1] = MFMA_SC(a3, b1, acc[3][1]);                           \
        __builtin_amdgcn_s_setprio(0);                                    \
    }

    // ---- prologue: fill 3 buffers (12 loads in flight) ----
    STAGE(0, 0); STAGE(1, 1); STAGE(2, 2);

    // ---- main loop: tiles 0..11 consumed, staging stays 3 ahead ----
    for (int t = 0; t < 12; t += 4) {
        STAGE(3, t + 3); VMCNT(12); BARS(); COMPUTE(0); BARS();
        STAGE(0, t + 4); VMCNT(12); BARS(); COMPUTE(1); BARS();
        STAGE(1, t + 5); VMCNT(12); BARS(); COMPUTE(2); BARS();
        STAGE(2, t + 6); VMCNT(12); BARS(); COMPUTE(3); BARS();
    }
    // ---- epilogue tiles 12..15: drain 12 -> 8 -> 4 -> 0 ----
    STAGE(3, 15); VMCNT(12); BARS(); COMPUTE(0); BARS();
    VMCNT(8);  BARS(); COMPUTE(1); BARS();
    VMCNT(4);  BARS(); COMPUTE(2); BARS();
    VMCNT(0);  BARS(); COMPUTE(3);

    // ---- C write + bias. 32x32 C/D frag: col=lane&31, row=(r&3)+8*(r>>2)+4*kh.
#pragma unroll
    for (int n = 0; n < 2; ++n) {
        int gcol = bn + wc * 64 + n * 32 + l31;
        float bv = bias[gcol];
#pragma unroll
        for (int m = 0; m < 4; ++m) {
            long rbase = bm + wr * 128 + m * 32 + 4 * kh;
#pragma unroll
            for (int r = 0; r < 16; ++r) {
                long grow = rbase + (r & 3) + 8 * (r >> 2);
                C[grow * NDIM + gcol] = acc[m][n][r] + bv;
            }
        }
    }
#undef STAGE
#undef COMPUTE
#undef LD32
}

extern "C" void kernel_launch(void* const* d_in, const int* in_sizes, int n_in,
                              void* d_out, int out_size, void* d_ws, size_t ws_size,
                              hipStream_t stream) {
    (void)in_sizes; (void)n_in; (void)out_size; (void)ws_size;
    const float* x = (const float*)d_in[0];
    const float* wk = (const float*)d_in[1];
    const float* bias = (const float*)d_in[2];
    float* out = (float*)d_out;

    char* xq = (char*)d_ws;                                       // 32 MB
    char* wT = (char*)d_ws + (size_t)MDIM * KDIM;                 // 4 MB

    quant_x_kernel<<<2048, 256, 0, stream>>>(x, xq, MDIM * KDIM / 16);
    quant_w_kernel<<<dim3(NDIM / 64, KDIM / 64), 256, 0, stream>>>(wk, wT);
    gemm_kernel<<<2048, 512, 0, stream>>>(xq, wT, bias, out);
}

// Round 5
// 254.078 us; speedup vs baseline: 1.0486x; 1.0486x over previous
//
#include <hip/hip_runtime.h>

#define MDIM 32768
#define NDIM 4096
#define KDIM 1024

typedef __attribute__((ext_vector_type(4))) float floatx4;
typedef __attribute__((ext_vector_type(16))) float float16v;
typedef __attribute__((ext_vector_type(4))) int int4v;
typedef __attribute__((ext_vector_type(8))) int int8v;

// ---- quantize x: f32 [M,K] -> fp8 e4m3 bytes [M,K] (RNE, saturating) ----
__global__ __launch_bounds__(256) void quant_x_kernel(
    const float* __restrict__ x, char* __restrict__ out, int n16) {
    int idx = blockIdx.x * blockDim.x + threadIdx.x;
    int stride = gridDim.x * blockDim.x;
    const floatx4* xv = (const floatx4*)x;
    int4v* ov = (int4v*)out;
    for (int i = idx; i < n16; i += stride) {
        int4v o;
#pragma unroll
        for (int j = 0; j < 4; ++j) {
            floatx4 v = xv[i * 4 + j];
            int pk = __builtin_amdgcn_cvt_pk_fp8_f32(v.x, v.y, 0, false);
            pk = __builtin_amdgcn_cvt_pk_fp8_f32(v.z, v.w, pk, true);
            o[j] = pk;
        }
        ov[i] = o;
    }
}

// ---- quantize + transpose w: f32 [K,N] -> fp8 e4m3 [N,K] ----
__global__ __launch_bounds__(256) void quant_w_kernel(
    const float* __restrict__ w, char* __restrict__ wT) {
    __shared__ char tile[64][68];
    int nbase = blockIdx.x * 64;
    int kbase = blockIdx.y * 64;
    int t = threadIdx.x;
#pragma unroll
    for (int i = 0; i < 4; ++i) {
        int fidx = t + i * 256;      // 1024 float4s per 64x64 tile
        int r = fidx >> 4;           // k row 0..63
        int c4 = fidx & 15;          // float4 col
        floatx4 v = *(const floatx4*)&w[(long)(kbase + r) * NDIM + nbase + c4 * 4];
        int pk = __builtin_amdgcn_cvt_pk_fp8_f32(v.x, v.y, 0, false);
        pk = __builtin_amdgcn_cvt_pk_fp8_f32(v.z, v.w, pk, true);
        *(int*)&tile[r][c4 * 4] = pk;
    }
    __syncthreads();
    int n = t >> 2, kq = (t & 3) * 16;
    int outw[4];
#pragma unroll
    for (int g = 0; g < 4; ++g) {
        int v = 0;
#pragma unroll
        for (int j = 0; j < 4; ++j)
            v |= ((int)(unsigned char)tile[kq + g * 4 + j][n]) << (8 * j);
        outw[g] = v;
    }
    *(int4v*)&wT[(long)(nbase + n) * KDIM + kbase + kq] = *(int4v*)outw;
}

// ======== GEMM: MX-fp8 (unit scales). A fp8 [M,K], BT fp8 [N,K], C f32 [M,N].
// 256x256 tile, BK=128 bytes, 8 K-tiles, 2 LDS bufs. Round-3 geometry +
// 4-phase T3 interleave: per tile {GLx8 next tile -> vmcnt(8) -> barrier},
// then 4 phases of {ds_read subtile -> barrier -> setprio(1) + 4 MFMA ->
// barrier}. vmcnt never drained mid-loop; newest in-flight load is ~4 phases
// old when waited. XOR swizzle chunk ^= row&7 (zero conflicts, verified).

#define GL(gp, lp)                                                 \
    __builtin_amdgcn_global_load_lds(                              \
        (const __attribute__((address_space(1))) void*)(gp),       \
        (__attribute__((address_space(3))) void*)(lp), 16, 0, 0)

#define VMCNT(n) asm volatile("s_waitcnt vmcnt(" #n ")" ::: "memory")
#define BARS()  { __builtin_amdgcn_s_barrier(); __builtin_amdgcn_sched_barrier(0); }
#define SP1 __builtin_amdgcn_s_setprio(1)
#define SP0 __builtin_amdgcn_s_setprio(0)

#define MFMA_SC(a_, b_, c_)                                               \
    __builtin_amdgcn_mfma_scale_f32_32x32x64_f8f6f4(                      \
        (a_), (b_), (c_), 0, 0, 0, 0x7F7F7F7F, 0, 0x7F7F7F7F)

__global__ __launch_bounds__(512) void gemm_kernel(
    const char* __restrict__ A, const char* __restrict__ BT,
    const float* __restrict__ bias, float* __restrict__ C) {
    __shared__ char lds[131072];   // buf d: A at d*32768, B at 65536 + d*32768

    const int T = threadIdx.x;
    const int lane = T & 63;
    const int w = T >> 6;            // wave 0..7
    const int wr = w >> 2;           // 0..1 (M)
    const int wc = w & 3;            // 0..3 (N)

    // XCD-aware bijective swizzle (2048 blocks % 8 == 0), bn-major chunks.
    const int sw = (blockIdx.x & 7) * 256 + (blockIdx.x >> 3);
    const int bn = (sw >> 7) * 256;      // 16 N-blocks
    const int bm = (sw & 127) * 256;     // 128 M-blocks

    // ---- staging (per-thread): LDS phys chunk (T&7) of slab-row (T>>3)
    // holds logical chunk (T&7)^((T>>3)&7) (both-sides XOR involution).
    const int cs = (T & 7) ^ ((T >> 3) & 7);
    const long aOff = (long)(bm + (T >> 3)) * KDIM + cs * 16;
    const long bOff = (long)(bn + (T >> 3)) * KDIM + cs * 16;
    const int dstB = (T >> 3) * 128 + (T & 7) * 16;

#define STAGE8(d_, t_) {                                                      \
        char* la_ = lds + (d_) * 32768 + dstB;                                \
        char* lb_ = lds + 65536 + (d_) * 32768 + dstB;                        \
        const char* ga_ = A + aOff + (t_) * 128;                              \
        const char* gb_ = BT + bOff + (t_) * 128;                             \
        GL(ga_, la_);                 GL(ga_ + 64 * KDIM, la_ + 8192);        \
        GL(ga_ + 128 * KDIM, la_ + 16384); GL(ga_ + 192 * KDIM, la_ + 24576); \
        GL(gb_, lb_);                 GL(gb_ + 64 * KDIM, lb_ + 8192);        \
        GL(gb_ + 128 * KDIM, lb_ + 16384); GL(gb_ + 192 * KDIM, lb_ + 24576); \
    }

    // ---- read-side addresses ----
    const int l31 = lane & 31;
    const int kh32 = (lane >> 5) * 32;        // k half offset within 64B half
    const int swz = (l31 & 7) << 4;           // row&7 == l31&7 for all frag rows
    const char* Abase = lds + (wr * 128 + l31) * 128;
    const char* Bbase = lds + 65536 + (wc * 64 + l31) * 128;

    float16v acc[4][2] = {};

#define LD32(dst_, base_, col0_) {                                        \
        int4v lo_ = *(const int4v*)((base_) + (((col0_) + 0) ^ swz));     \
        int4v hi_ = *(const int4v*)((base_) + (((col0_) + 16) ^ swz));    \
        dst_[0] = lo_[0]; dst_[1] = lo_[1]; dst_[2] = lo_[2]; dst_[3] = lo_[3]; \
        dst_[4] = hi_[0]; dst_[5] = hi_[1]; dst_[6] = hi_[2]; dst_[7] = hi_[3]; \
    }

#define MF(x_, y_, m_, n_) acc[m_][n_] = MFMA_SC(x_, y_, acc[m_][n_])

    // Tile body: stage next tile (front-loaded), counted wait, 4 phases.
#define TILE(c_, stage_, vm_) {                                           \
        stage_;                                                           \
        vm_;                                                              \
        BARS();                                                           \
        const char* Ab_ = Abase + (c_) * 32768;                           \
        const char* Bb_ = Bbase + (c_) * 32768;                           \
        int8v a0, a1, a2, a3, b0, b1;                                     \
        /* P0: kk0, m-pair 0 */                                           \
        LD32(b0, Bb_, kh32);          LD32(b1, Bb_ + 4096, kh32);         \
        LD32(a0, Ab_, kh32);          LD32(a1, Ab_ + 4096, kh32);         \
        BARS();                                                           \
        SP1; MF(a0, b0, 0, 0); MF(a0, b1, 0, 1);                          \
             MF(a1, b0, 1, 0); MF(a1, b1, 1, 1); SP0;                     \
        BARS();                                                           \
        /* P1: kk0, m-pair 1 */                                           \
        LD32(a2, Ab_ + 8192, kh32);   LD32(a3, Ab_ + 12288, kh32);        \
        BARS();                                                           \
        SP1; MF(a2, b0, 2, 0); MF(a2, b1, 2, 1);                          \
             MF(a3, b0, 3, 0); MF(a3, b1, 3, 1); SP0;                     \
        BARS();                                                           \
        /* P2: kk1, m-pair 0 */                                           \
        LD32(b0, Bb_, kh32 + 64);     LD32(b1, Bb_ + 4096, kh32 + 64);    \
        LD32(a0, Ab_, kh32 + 64);     LD32(a1, Ab_ + 4096, kh32 + 64);    \
        BARS();                                                           \
        SP1; MF(a0, b0, 0, 0); MF(a0, b1, 0, 1);                          \
             MF(a1, b0, 1, 0); MF(a1, b1, 1, 1); SP0;                     \
        BARS();                                                           \
        /* P3: kk1, m-pair 1 */                                           \
        LD32(a2, Ab_ + 8192, kh32 + 64); LD32(a3, Ab_ + 12288, kh32 + 64); \
        BARS();                                                           \
        SP1; MF(a2, b0, 2, 0); MF(a2, b1, 2, 1);                          \
             MF(a3, b0, 3, 0); MF(a3, b1, 3, 1); SP0;                     \
        BARS();                                                           \
    }

    // ---- prologue + 8 fully-unrolled tiles (static buf indices) ----
    STAGE8(0, 0);
    TILE(0, STAGE8(1, 1), VMCNT(8));
    TILE(1, STAGE8(0, 2), VMCNT(8));
    TILE(0, STAGE8(1, 3), VMCNT(8));
    TILE(1, STAGE8(0, 4), VMCNT(8));
    TILE(0, STAGE8(1, 5), VMCNT(8));
    TILE(1, STAGE8(0, 6), VMCNT(8));
    TILE(0, STAGE8(1, 7), VMCNT(8));
    TILE(1, (void)0,      VMCNT(0));

    // ---- C write + bias. 32x32 C/D frag: col=lane&31, row=(r&3)+8*(r>>2)+4*kh.
    const int kh = kh32 >> 5;
#pragma unroll
    for (int n = 0; n < 2; ++n) {
        int gcol = bn + wc * 64 + n * 32 + l31;
        float bv = bias[gcol];
#pragma unroll
        for (int m = 0; m < 4; ++m) {
            long rbase = bm + wr * 128 + m * 32 + 4 * kh;
#pragma unroll
            for (int r = 0; r < 16; ++r) {
                long grow = rbase + (r & 3) + 8 * (r >> 2);
                C[grow * NDIM + gcol] = acc[m][n][r] + bv;
            }
        }
    }
#undef STAGE8
#undef TILE
#undef LD32
#undef MF
}

extern "C" void kernel_launch(void* const* d_in, const int* in_sizes, int n_in,
                              void* d_out, int out_size, void* d_ws, size_t ws_size,
                              hipStream_t stream) {
    (void)in_sizes; (void)n_in; (void)out_size; (void)ws_size;
    const float* x = (const float*)d_in[0];
    const float* wk = (const float*)d_in[1];
    const float* bias = (const float*)d_in[2];
    float* out = (float*)d_out;

    char* xq = (char*)d_ws;                                       // 32 MB
    char* wT = (char*)d_ws + (size_t)MDIM * KDIM;                 // 4 MB

    quant_x_kernel<<<2048, 256, 0, stream>>>(x, xq, MDIM * KDIM / 16);
    quant_w_kernel<<<dim3(NDIM / 64, KDIM / 64), 256, 0, stream>>>(wk, wT);
    gemm_kernel<<<2048, 512, 0, stream>>>(xq, wT, bias, out);
}

// Round 6
// 226.402 us; speedup vs baseline: 1.1768x; 1.1222x over previous
//
#include <hip/hip_runtime.h>

#define MDIM 32768
#define NDIM 4096
#define KDIM 1024

typedef __attribute__((ext_vector_type(4))) float floatx4;
typedef __attribute__((ext_vector_type(16))) float float16v;
typedef __attribute__((ext_vector_type(4))) int int4v;
typedef __attribute__((ext_vector_type(8))) int int8v;

// ---- quantize x: f32 [M,K] -> fp8 e4m3 bytes [M,K] (RNE, saturating) ----
__global__ __launch_bounds__(256) void quant_x_kernel(
    const float* __restrict__ x, char* __restrict__ out, int n16) {
    int idx = blockIdx.x * blockDim.x + threadIdx.x;
    int stride = gridDim.x * blockDim.x;
    const floatx4* xv = (const floatx4*)x;
    int4v* ov = (int4v*)out;
    for (int i = idx; i < n16; i += stride) {
        int4v o;
#pragma unroll
        for (int j = 0; j < 4; ++j) {
            floatx4 v = __builtin_nontemporal_load(&xv[i * 4 + j]);  // x never reused
            int pk = __builtin_amdgcn_cvt_pk_fp8_f32(v.x, v.y, 0, false);
            pk = __builtin_amdgcn_cvt_pk_fp8_f32(v.z, v.w, pk, true);
            o[j] = pk;
        }
        ov[i] = o;
    }
}

// ---- quantize + transpose w: f32 [K,N] -> fp8 e4m3 [N,K] ----
__global__ __launch_bounds__(256) void quant_w_kernel(
    const float* __restrict__ w, char* __restrict__ wT) {
    __shared__ char tile[64][68];
    int nbase = blockIdx.x * 64;
    int kbase = blockIdx.y * 64;
    int t = threadIdx.x;
#pragma unroll
    for (int i = 0; i < 4; ++i) {
        int fidx = t + i * 256;      // 1024 float4s per 64x64 tile
        int r = fidx >> 4;           // k row 0..63
        int c4 = fidx & 15;          // float4 col
        floatx4 v = *(const floatx4*)&w[(long)(kbase + r) * NDIM + nbase + c4 * 4];
        int pk = __builtin_amdgcn_cvt_pk_fp8_f32(v.x, v.y, 0, false);
        pk = __builtin_amdgcn_cvt_pk_fp8_f32(v.z, v.w, pk, true);
        *(int*)&tile[r][c4 * 4] = pk;
    }
    __syncthreads();
    int n = t >> 2, kq = (t & 3) * 16;
    int outw[4];
#pragma unroll
    for (int g = 0; g < 4; ++g) {
        int v = 0;
#pragma unroll
        for (int j = 0; j < 4; ++j)
            v |= ((int)(unsigned char)tile[kq + g * 4 + j][n]) << (8 * j);
        outw[g] = v;
    }
    *(int4v*)&wT[(long)(nbase + n) * KDIM + kbase + kq] = *(int4v*)outw;
}

// ======== GEMM: MX-fp8 (unit scales). A fp8 [M,K], BT fp8 [N,K], C f32 [M,N].
// 256x256 tile, BK=128 bytes, 8 K-tiles, 2 LDS bufs, round-3 schedule:
// {STAGE next -> vmcnt(8) -> barrier -> 16 MFMA -> barrier}, vmcnt never
// drained mid-loop. XOR swizzle chunk ^= row&7 (zero conflicts, verified).
// NEW: bm-major block order (A-panel shared by 16 consecutive blocks in one
// XCD's chunk; B L3-resident) + non-temporal C stores (don't evict A/B).

#define GL(gp, lp)                                                 \
    __builtin_amdgcn_global_load_lds(                              \
        (const __attribute__((address_space(1))) void*)(gp),       \
        (__attribute__((address_space(3))) void*)(lp), 16, 0, 0)

#define VMCNT(n) asm volatile("s_waitcnt vmcnt(" #n ")" ::: "memory")
#define BARS()  { __builtin_amdgcn_s_barrier(); __builtin_amdgcn_sched_barrier(0); }

#define MFMA_SC(a_, b_, c_)                                               \
    __builtin_amdgcn_mfma_scale_f32_32x32x64_f8f6f4(                      \
        (a_), (b_), (c_), 0, 0, 0, 0x7F7F7F7F, 0, 0x7F7F7F7F)

__global__ __launch_bounds__(512) void gemm_kernel(
    const char* __restrict__ A, const char* __restrict__ BT,
    const float* __restrict__ bias, float* __restrict__ C) {
    __shared__ char lds[131072];   // buf d: A at d*32768, B at 65536 + d*32768

    const int T = threadIdx.x;
    const int lane = T & 63;
    const int w = T >> 6;            // wave 0..7
    const int wr = w >> 2;           // 0..1 (M)
    const int wc = w & 3;            // 0..3 (N)

    // XCD-aware bijective swizzle (2048 blocks % 8 == 0), bm-MAJOR within
    // each XCD chunk: 16 consecutive blocks share one A panel (L2-resident).
    const int sw = (blockIdx.x & 7) * 256 + (blockIdx.x >> 3);
    const int bm = (sw >> 4) * 256;      // 128 M-blocks (major)
    const int bn = (sw & 15) * 256;      // 16 N-blocks (minor)

    // ---- staging (per-thread): LDS phys chunk (T&7) of slab-row (T>>3)
    // holds logical chunk (T&7)^((T>>3)&7) (both-sides XOR involution).
    const int cs = (T & 7) ^ ((T >> 3) & 7);
    const long aOff = (long)(bm + (T >> 3)) * KDIM + cs * 16;
    const long bOff = (long)(bn + (T >> 3)) * KDIM + cs * 16;
    const int dstB = (T >> 3) * 128 + (T & 7) * 16;

#define STAGE8(d_, t_) {                                                      \
        char* la_ = lds + (d_) * 32768 + dstB;                                \
        char* lb_ = lds + 65536 + (d_) * 32768 + dstB;                        \
        const char* ga_ = A + aOff + (t_) * 128;                              \
        const char* gb_ = BT + bOff + (t_) * 128;                             \
        GL(ga_, la_);                 GL(ga_ + 64 * KDIM, la_ + 8192);        \
        GL(ga_ + 128 * KDIM, la_ + 16384); GL(ga_ + 192 * KDIM, la_ + 24576); \
        GL(gb_, lb_);                 GL(gb_ + 64 * KDIM, lb_ + 8192);        \
        GL(gb_ + 128 * KDIM, lb_ + 16384); GL(gb_ + 192 * KDIM, lb_ + 24576); \
    }

    // ---- read-side addresses ----
    const int l31 = lane & 31;
    const int kh = lane >> 5;                 // k half-wave
    const int swz = (l31 & 7) << 4;           // row&7 == l31&7 for all frag rows
    const char* Abase = lds + (wr * 128 + l31) * 128;
    const char* Bbase = lds + 65536 + (wc * 64 + l31) * 128;

    float16v acc[4][2] = {};

#define LD32(dst_, base_, col0_) {                                        \
        int4v lo_ = *(const int4v*)((base_) + (((col0_) + 0) ^ swz));     \
        int4v hi_ = *(const int4v*)((base_) + (((col0_) + 16) ^ swz));    \
        dst_[0] = lo_[0]; dst_[1] = lo_[1]; dst_[2] = lo_[2]; dst_[3] = lo_[3]; \
        dst_[4] = hi_[0]; dst_[5] = hi_[1]; dst_[6] = hi_[2]; dst_[7] = hi_[3]; \
    }

#define COMPUTE(d_) {                                                     \
        const char* ap_ = Abase + (d_) * 32768;                           \
        const char* bp_ = Bbase + (d_) * 32768;                           \
        _Pragma("unroll")                                                 \
        for (int kk = 0; kk < 2; ++kk) {                                  \
            const int col0 = kk * 64 + kh * 32;                           \
            int8v b0, b1, a0, a1, a2, a3;                                 \
            LD32(b0, bp_, col0); LD32(b1, bp_ + 4096, col0);              \
            LD32(a0, ap_, col0);          LD32(a1, ap_ + 4096, col0);     \
            LD32(a2, ap_ + 8192, col0);   LD32(a3, ap_ + 12288, col0);    \
            __builtin_amdgcn_s_setprio(1);                                \
            acc[0][0] = MFMA_SC(a0, b0, acc[0][0]);                       \
            acc[0][1] = MFMA_SC(a0, b1, acc[0][1]);                       \
            acc[1][0] = MFMA_SC(a1, b0, acc[1][0]);                       \
            acc[1][1] = MFMA_SC(a1, b1, acc[1][1]);                       \
            acc[2][0] = MFMA_SC(a2, b0, acc[2][0]);                       \
            acc[2][1] = MFMA_SC(a2, b1, acc[2][1]);                       \
            acc[3][0] = MFMA_SC(a3, b0, acc[3][0]);                       \
            acc[3][1] = MFMA_SC(a3, b1, acc[3][1]);                       \
            __builtin_amdgcn_s_setprio(0);                                \
        }                                                                 \
    }

    // ---- pipeline: 8 K-tiles, 2 bufs, fully unrolled, vmcnt never 0 mid-loop.
    STAGE8(0, 0);
    STAGE8(1, 1); VMCNT(8); BARS(); COMPUTE(0); BARS();
    STAGE8(0, 2); VMCNT(8); BARS(); COMPUTE(1); BARS();
    STAGE8(1, 3); VMCNT(8); BARS(); COMPUTE(0); BARS();
    STAGE8(0, 4); VMCNT(8); BARS(); COMPUTE(1); BARS();
    STAGE8(1, 5); VMCNT(8); BARS(); COMPUTE(0); BARS();
    STAGE8(0, 6); VMCNT(8); BARS(); COMPUTE(1); BARS();
    STAGE8(1, 7); VMCNT(8); BARS(); COMPUTE(0); BARS();
    VMCNT(0);  BARS(); COMPUTE(1);

    // ---- C write + bias (non-temporal: C is write-once, keep L2/L3 for A/B).
    // 32x32 C/D frag: col=lane&31, row=(r&3)+8*(r>>2)+4*kh.
#pragma unroll
    for (int n = 0; n < 2; ++n) {
        int gcol = bn + wc * 64 + n * 32 + l31;
        float bv = bias[gcol];
#pragma unroll
        for (int m = 0; m < 4; ++m) {
            long rbase = bm + wr * 128 + m * 32 + 4 * kh;
#pragma unroll
            for (int r = 0; r < 16; ++r) {
                long grow = rbase + (r & 3) + 8 * (r >> 2);
                __builtin_nontemporal_store(acc[m][n][r] + bv, &C[grow * NDIM + gcol]);
            }
        }
    }
#undef STAGE8
#undef COMPUTE
#undef LD32
}

extern "C" void kernel_launch(void* const* d_in, const int* in_sizes, int n_in,
                              void* d_out, int out_size, void* d_ws, size_t ws_size,
                              hipStream_t stream) {
    (void)in_sizes; (void)n_in; (void)out_size; (void)ws_size;
    const float* x = (const float*)d_in[0];
    const float* wk = (const float*)d_in[1];
    const float* bias = (const float*)d_in[2];
    float* out = (float*)d_out;

    char* xq = (char*)d_ws;                                       // 32 MB
    char* wT = (char*)d_ws + (size_t)MDIM * KDIM;                 // 4 MB

    quant_x_kernel<<<2048, 256, 0, stream>>>(x, xq, MDIM * KDIM / 16);
    quant_w_kernel<<<dim3(NDIM / 64, KDIM / 64), 256, 0, stream>>>(wk, wT);
    gemm_kernel<<<2048, 512, 0, stream>>>(xq, wT, bias, out);
}